// Round 1
// baseline (475.982 us; speedup 1.0000x reference)
//
#include <hip/hip_runtime.h>

typedef unsigned short u16;
typedef __attribute__((ext_vector_type(8))) u16 u16x8;
typedef __attribute__((ext_vector_type(8))) __bf16 bf16x8;
typedef __attribute__((ext_vector_type(4))) float f32x4;

#define NN 8192
#define FIN 256
#define FOUT 128

__device__ __forceinline__ u16 f2bf(float f) {
  unsigned u = __float_as_uint(f);
  u += 0x7fffu + ((u >> 16) & 1u);   // RNE
  return (u16)(u >> 16);
}
__device__ __forceinline__ float bf2f(u16 s) {
  return __uint_as_float(((unsigned)s) << 16);
}

// ---------------- kernel 0: W -> bf16 hi/lo split ----------------
__global__ __launch_bounds__(256) void k_splitw(const float* __restrict__ W,
                                                u16* __restrict__ Whi,
                                                u16* __restrict__ Wlo) {
  int t = blockIdx.x * 256 + threadIdx.x;   // 128 blocks * 256 = 32768 = FOUT*FIN
  float w = W[t];
  u16 hi = f2bf(w);
  Whi[t] = hi;
  Wlo[t] = f2bf(w - bf2f(hi));
}

// ---------------- kernel 1: Xp = X@W.T + b (hi/lo MFMA), tables, swizzled bf16 Xp ----
// block = 256 thr (4 waves), covers 32 rows x 128 cols.
// wave w: mt = w&1 (row half), nh = w>>1 (feature half of 64).
__global__ __launch_bounds__(256) void k_xp(const float* __restrict__ X,
    const u16* __restrict__ Whi, const u16* __restrict__ Wlo,
    const float* __restrict__ bias, const float* __restrict__ S,
    u16* __restrict__ Bsw, float* __restrict__ alphaA, float* __restrict__ cexpA,
    float* __restrict__ jbF, u16* __restrict__ jebA, u16* __restrict__ jeb2A) {
  __shared__ float Xs[32 * 129];   // +1 pad: bank = (row + f) % 32
  __shared__ float Ss[256];
  const int tid = threadIdx.x;
  Ss[tid] = S[tid];
  const int i0 = blockIdx.x * 32;
  const int w = tid >> 6, l = tid & 63;
  const int mt = w & 1, nh = w >> 1;
  const int li = l & 15, quad = l >> 4;
  const int row = i0 + mt * 16 + li;

  f32x4 acc[4];
#pragma unroll
  for (int nt4 = 0; nt4 < 4; ++nt4) acc[nt4] = f32x4{0.f, 0.f, 0.f, 0.f};

  const float* xrow = X + (size_t)row * FIN + quad * 8;
  for (int k0 = 0; k0 < FIN; k0 += 32) {
    float4 xa = *(const float4*)(xrow + k0);
    float4 xb = *(const float4*)(xrow + k0 + 4);
    float xv[8] = {xa.x, xa.y, xa.z, xa.w, xb.x, xb.y, xb.z, xb.w};
    u16x8 ahiu, alou;
#pragma unroll
    for (int jj = 0; jj < 8; ++jj) {
      u16 h = f2bf(xv[jj]);
      ahiu[jj] = h;
      alou[jj] = f2bf(xv[jj] - bf2f(h));
    }
    bf16x8 ahi = __builtin_bit_cast(bf16x8, ahiu);
    bf16x8 alo = __builtin_bit_cast(bf16x8, alou);
#pragma unroll
    for (int nt4 = 0; nt4 < 4; ++nt4) {
      int f = nh * 64 + nt4 * 16 + li;
      size_t wofs = (size_t)f * FIN + k0 + quad * 8;
      bf16x8 bhi = __builtin_bit_cast(bf16x8, *(const u16x8*)(Whi + wofs));
      bf16x8 blo = __builtin_bit_cast(bf16x8, *(const u16x8*)(Wlo + wofs));
      acc[nt4] = __builtin_amdgcn_mfma_f32_16x16x32_bf16(ahi, bhi, acc[nt4], 0, 0, 0);
      acc[nt4] = __builtin_amdgcn_mfma_f32_16x16x32_bf16(alo, bhi, acc[nt4], 0, 0, 0);
      acc[nt4] = __builtin_amdgcn_mfma_f32_16x16x32_bf16(ahi, blo, acc[nt4], 0, 0, 0);
    }
  }
  // C/D layout (verified): col = lane&15, row = quad*4 + reg
#pragma unroll
  for (int nt4 = 0; nt4 < 4; ++nt4) {
    int f = nh * 64 + nt4 * 16 + li;
    float bv = bias[f];
#pragma unroll
    for (int r = 0; r < 4; ++r)
      Xs[(mt * 16 + quad * 4 + r) * 129 + f] = acc[nt4][r] + bv;
  }
  __syncthreads();

  // Phase A: swizzled bf16 Xp: slot[(jblock)*8 + nt][lane] holds
  // Xp[jblock*32 + (lane>>4)*8 + jj][nt*16 + (lane&15)] for jj=0..7 (16B)
#pragma unroll
  for (int s = 0; s < 2; ++s) {
    int nt = w + s * 4;
    int f = nt * 16 + li;
    int jl = quad * 8;
    u16x8 ou;
#pragma unroll
    for (int jj = 0; jj < 8; ++jj) ou[jj] = f2bf(Xs[(jl + jj) * 129 + f]);
    *(u16x8*)(Bsw + (((size_t)(i0 >> 5)) * 8 + nt) * 512 + (size_t)l * 8) = ou;
  }

  // Phase B: alpha/beta and exp tables (full fp32)
  const int r = tid >> 3, sub = tid & 7;
  float pa = 0.f, pb = 0.f;
#pragma unroll
  for (int m = 0; m < 16; ++m) {
    int f = sub + m * 8;
    float x = Xs[r * 129 + f];
    pa += x * Ss[f];
    pb += x * Ss[128 + f];
  }
  pa += __shfl_xor(pa, 1); pa += __shfl_xor(pa, 2); pa += __shfl_xor(pa, 4);
  pb += __shfl_xor(pb, 1); pb += __shfl_xor(pb, 2); pb += __shfl_xor(pb, 4);
  if (sub == 0) {
    int i = i0 + r;
    alphaA[i] = pa;
    cexpA[i] = expf(-0.99f * pa);     // e^{0.01a - a}
    jbF[i] = pb;
    jebA[i] = f2bf(expf(pb));         // e^{b}
    jeb2A[i] = f2bf(expf(0.01f * pb)); // e^{0.01 b}
  }
}

// ---------------- kernel 2: masked softmax-weighted aggregation ----------------
// 256 blocks (32 rows each) x 8 waves (each a K-chunk of 1024 columns).
__global__ __launch_bounds__(512, 2) void k_gat(const int* __restrict__ adj,
    const u16* __restrict__ Bsw, const float* __restrict__ alphaA,
    const float* __restrict__ cexpA, const float* __restrict__ jbF,
    const u16* __restrict__ jebA, const u16* __restrict__ jeb2A,
    float* __restrict__ out) {
  __shared__ float sacc[32 * 132];  // stride 132: bank = (row*4 + f) % 32 -> 2-way max
  __shared__ float sden[32];
  const int tid = threadIdx.x;
  for (int t = tid; t < 32 * 132; t += 512) sacc[t] = 0.f;
  if (tid < 32) sden[tid] = 0.f;
  __syncthreads();

  const int w = tid >> 6, l = tid & 63;
  const int li = l & 15, quad = l >> 4;
  const int i0 = blockIdx.x * 32;
  const int im0 = i0 + li, im1 = im0 + 16;
  const float nega0 = -alphaA[im0], nega1 = -alphaA[im1];
  const float c0 = cexpA[im0], c1 = cexpA[im1];
  const int* ar0 = adj + (size_t)im0 * NN;
  const int* ar1 = adj + (size_t)im1 * NN;

  f32x4 acc0[8], acc1[8];
#pragma unroll
  for (int nt = 0; nt < 8; ++nt) {
    acc0[nt] = f32x4{0.f, 0.f, 0.f, 0.f};
    acc1[nt] = f32x4{0.f, 0.f, 0.f, 0.f};
  }
  float den0 = 0.f, den1 = 0.f;

  const int jbeg = w * 1024, jend = jbeg + 1024;
  for (int j0 = jbeg; j0 < jend; j0 += 32) {
    const int jq = j0 + quad * 8;
    // adj in exact A-fragment layout: m = lane&15, k = quad*8 + jj
    int4 a00 = *(const int4*)(ar0 + jq);
    int4 a01 = *(const int4*)(ar0 + jq + 4);
    int4 a10 = *(const int4*)(ar1 + jq);
    int4 a11 = *(const int4*)(ar1 + jq + 4);
    float4 b0 = *(const float4*)(jbF + jq);
    float4 b1 = *(const float4*)(jbF + jq + 4);
    u16x8 ebj = *(const u16x8*)(jebA + jq);
    u16x8 e2j = *(const u16x8*)(jeb2A + jq);
    int a0v[8] = {a00.x, a00.y, a00.z, a00.w, a01.x, a01.y, a01.z, a01.w};
    int a1v[8] = {a10.x, a10.y, a10.z, a10.w, a11.x, a11.y, a11.z, a11.w};
    float bv[8] = {b0.x, b0.y, b0.z, b0.w, b1.x, b1.y, b1.z, b1.w};
    u16x8 af0, af1;
#pragma unroll
    for (int jj = 0; jj < 8; ++jj) {
      float bf = bv[jj];
      float eb = bf2f(ebj[jj]);
      float e2 = bf2f(e2j[jj]);
      int jg = jq + jj;
      float w0 = (bf >= nega0) ? eb : c0 * e2;
      w0 = (a0v[jj] != 0 || jg == im0) ? w0 : 0.f;
      u16 q0 = f2bf(w0);
      af0[jj] = q0;
      den0 += bf2f(q0);     // den from the same bf16 weights as num
      float w1 = (bf >= nega1) ? eb : c1 * e2;
      w1 = (a1v[jj] != 0 || jg == im1) ? w1 : 0.f;
      u16 q1 = f2bf(w1);
      af1[jj] = q1;
      den1 += bf2f(q1);
    }
    bf16x8 A0 = __builtin_bit_cast(bf16x8, af0);
    bf16x8 A1 = __builtin_bit_cast(bf16x8, af1);
    const u16* bb = Bsw + ((size_t)(j0 >> 5) * 8) * 512 + (size_t)l * 8;
#pragma unroll
    for (int nt = 0; nt < 8; ++nt) {
      bf16x8 B = __builtin_bit_cast(bf16x8, *(const u16x8*)(bb + nt * 512));
      acc0[nt] = __builtin_amdgcn_mfma_f32_16x16x32_bf16(A0, B, acc0[nt], 0, 0, 0);
      acc1[nt] = __builtin_amdgcn_mfma_f32_16x16x32_bf16(A1, B, acc1[nt], 0, 0, 0);
    }
  }

  // fold den over the 4 quads (lanes l, l^16, l^32, l^48 share a row)
  den0 += __shfl_xor(den0, 16); den0 += __shfl_xor(den0, 32);
  den1 += __shfl_xor(den1, 16); den1 += __shfl_xor(den1, 32);
  if (l < 16) { atomicAdd(&sden[li], den0); atomicAdd(&sden[16 + li], den1); }

  // C/D: col = lane&15 (feature), row = quad*4 + reg
#pragma unroll
  for (int nt = 0; nt < 8; ++nt) {
#pragma unroll
    for (int r = 0; r < 4; ++r) {
      atomicAdd(&sacc[(quad * 4 + r) * 132 + nt * 16 + li], acc0[nt][r]);
      atomicAdd(&sacc[(16 + quad * 4 + r) * 132 + nt * 16 + li], acc1[nt][r]);
    }
  }
  __syncthreads();

  // epilogue: wave w -> feature chunk [w*16, w*16+16)
  const int orow = l & 31, fh = l >> 5;
  const int fbase = w * 16 + fh * 8;
  const float* p = &sacc[orow * 132 + fbase];
  float4 v0 = *(const float4*)p;
  float4 v1 = *(const float4*)(p + 4);
  float rd = 1.f / sden[orow];
  float o[8] = {v0.x, v0.y, v0.z, v0.w, v1.x, v1.y, v1.z, v1.w};
#pragma unroll
  for (int jj = 0; jj < 8; ++jj) {
    float v = o[jj] * rd;
    o[jj] = 1.f / (1.f + __expf(-v));
  }
  float* op = out + (size_t)(i0 + orow) * FOUT + fbase;
  *(float4*)op = make_float4(o[0], o[1], o[2], o[3]);
  *(float4*)(op + 4) = make_float4(o[4], o[5], o[6], o[7]);
}

extern "C" void kernel_launch(void* const* d_in, const int* in_sizes, int n_in,
                              void* d_out, int out_size, void* d_ws, size_t ws_size,
                              hipStream_t stream) {
  const float* X = (const float*)d_in[0];     // 8192 x 256 f32
  const int* adj = (const int*)d_in[1];       // 8192 x 8192 i32
  const float* W = (const float*)d_in[2];     // 128 x 256 f32
  const float* bias = (const float*)d_in[3];  // 128 f32
  const float* S = (const float*)d_in[4];     // 256 f32
  float* out = (float*)d_out;

  char* ws = (char*)d_ws;                     // ~2.25 MB used
  u16* Bsw     = (u16*)(ws);                      // 2,097,152 B
  u16* Whi     = (u16*)(ws + 2097152);            //    65,536 B
  u16* Wlo     = (u16*)(ws + 2162688);            //    65,536 B
  float* alphaA = (float*)(ws + 2228224);         //    32,768 B
  float* cexpA  = (float*)(ws + 2260992);         //    32,768 B
  float* jbF    = (float*)(ws + 2293760);         //    32,768 B
  u16* jebA    = (u16*)(ws + 2326528);            //    16,384 B
  u16* jeb2A   = (u16*)(ws + 2342912);            //    16,384 B -> end 2,359,296

  hipLaunchKernelGGL(k_splitw, dim3(128), dim3(256), 0, stream, W, Whi, Wlo);
  hipLaunchKernelGGL(k_xp, dim3(256), dim3(256), 0, stream, X, Whi, Wlo, bias, S,
                     Bsw, alphaA, cexpA, jbF, jebA, jeb2A);
  hipLaunchKernelGGL(k_gat, dim3(256), dim3(512), 0, stream, adj, Bsw, alphaA, cexpA,
                     jbF, jebA, jeb2A, out);
}